// Round 11
// baseline (422.074 us; speedup 1.0000x reference)
//
#include <hip/hip_runtime.h>
#include <hip/hip_bf16.h>
#include <math.h>

#define FIN 256
#define C2  16
#define NEG 0.2f
#define LOG2E 1.4426950408889634f

typedef short bf16x8 __attribute__((ext_vector_type(8)));
typedef float f32x4v __attribute__((ext_vector_type(4)));
typedef float f32x2 __attribute__((ext_vector_type(2)));

__device__ __forceinline__ float bf2f(unsigned short u) {
  union { float f; unsigned int i; } c; c.i = ((unsigned int)u) << 16; return c.f;
}
__device__ __forceinline__ unsigned short f2bf(float f) {
  __hip_bfloat16 b = __float2bfloat16(f);
  return *(unsigned short*)&b;
}
__device__ __forceinline__ f32x2 bfpair(unsigned int u) {
  union { float f; unsigned int i; } lo, hi;
  lo.i = u << 16;
  hi.i = u & 0xffff0000u;
  f32x2 r; r.x = lo.f; r.y = hi.f; return r;
}

// ---------------- CSR build (both graphs, int4-vectorized) ----------------
__global__ __launch_bounds__(256) void deg_kernel(const int* __restrict__ ei1,
    const int* __restrict__ ei2, int* __restrict__ deg, int E, int N) {
  int EQ = (E + 3) >> 2;
  int q = blockIdx.x * 256 + threadIdx.x;
  if (q >= 2 * EQ) return;
  int g = q >= EQ;
  int lq = g ? q - EQ : q;
  const int* dstp = (g ? ei2 : ei1) + E;
  int base = g * N;
  int e0 = lq * 4;
  if (e0 + 3 < E) {
    int4 d4 = *(const int4*)&dstp[e0];
    atomicAdd(&deg[base + d4.x], 1);
    atomicAdd(&deg[base + d4.y], 1);
    atomicAdd(&deg[base + d4.z], 1);
    atomicAdd(&deg[base + d4.w], 1);
  } else {
    for (int k = 0; k < 4 && e0 + k < E; k++)
      atomicAdd(&deg[base + dstp[e0 + k]], 1);
  }
}

__global__ __launch_bounds__(1024) void scan_part_kernel(const int* __restrict__ deg,
    int* __restrict__ offs, int* __restrict__ partials, int n) {
  __shared__ int wsum[16], wpref[16];
  int tid = threadIdx.x, lane = tid & 63, wid = tid >> 6;
  int idx = blockIdx.x * 1024 + tid;
  int v = (idx < n) ? deg[idx] : 0;
  int s = v;
#pragma unroll
  for (int o = 1; o < 64; o <<= 1) {
    int t = __shfl_up(s, o, 64);
    if (lane >= o) s += t;
  }
  if (lane == 63) wsum[wid] = s;
  __syncthreads();
  if (tid < 16) {
    int t = wsum[tid];
    int ss = t;
#pragma unroll
    for (int o = 1; o < 16; o <<= 1) {
      int u = __shfl_up(ss, o, 16);
      if (tid >= o) ss += u;
    }
    wpref[tid] = ss - t;
    if (tid == 15) partials[blockIdx.x] = ss;
  }
  __syncthreads();
  if (idx < n) offs[idx] = wpref[wid] + s - v;
}

__global__ __launch_bounds__(1024) void scan_fix_kernel(int* __restrict__ offs,
    const int* __restrict__ partials, int nb, int n) {
  __shared__ int wsum[16], wpref[16];
  __shared__ int carry_s;
  int tid = threadIdx.x, lane = tid & 63, wid = tid >> 6;
  int v = (tid < nb) ? partials[tid] : 0;
  int s = v;
#pragma unroll
  for (int o = 1; o < 64; o <<= 1) {
    int t = __shfl_up(s, o, 64);
    if (lane >= o) s += t;
  }
  if (lane == 63) wsum[wid] = s;
  __syncthreads();
  if (tid < 16) {
    int t = wsum[tid];
    int ss = t;
#pragma unroll
    for (int o = 1; o < 16; o <<= 1) {
      int u = __shfl_up(ss, o, 16);
      if (tid >= o) ss += u;
    }
    wpref[tid] = ss - t;
  }
  __syncthreads();
  s += wpref[wid];
  int b = blockIdx.x;
  if (b == 0) {
    if (tid == nb - 1) offs[n] = s;
  } else if (tid == b - 1) {
    carry_s = s;
  }
  __syncthreads();
  if (b > 0) {
    int idx = b * 1024 + tid;
    if (idx < n) offs[idx] += carry_s;
  }
}

__global__ __launch_bounds__(256) void fill_kernel(const int* __restrict__ ei1,
    const int* __restrict__ ei2, const int* __restrict__ offs,
    int* __restrict__ cnt, int* __restrict__ csr, int E, int N) {
  int EQ = (E + 3) >> 2;
  int q = blockIdx.x * 256 + threadIdx.x;
  if (q >= 2 * EQ) return;
  int g = q >= EQ;
  int lq = g ? q - EQ : q;
  const int* ei = g ? ei2 : ei1;
  int base = g * N;
  int e0 = lq * 4;
  if (e0 + 3 < E) {
    int4 s4 = *(const int4*)&ei[e0];
    int4 d4 = *(const int4*)&ei[E + e0];
    int n0 = base + d4.x, n1 = base + d4.y, n2 = base + d4.z, n3 = base + d4.w;
    csr[offs[n0] + atomicAdd(&cnt[n0], 1)] = base + s4.x;
    csr[offs[n1] + atomicAdd(&cnt[n1], 1)] = base + s4.y;
    csr[offs[n2] + atomicAdd(&cnt[n2], 1)] = base + s4.z;
    csr[offs[n3] + atomicAdd(&cnt[n3], 1)] = base + s4.w;
  } else {
    for (int k = 0; k < 4 && e0 + k < E; k++) {
      int node = base + ei[E + e0 + k];
      csr[offs[node] + atomicAdd(&cnt[node], 1)] = base + ei[e0 + k];
    }
  }
}

// ---------------- weight converts (one launch) ----------------
__global__ __launch_bounds__(256) void cvt_w_kernel(const float* __restrict__ W1l,
    const float* __restrict__ W1r, const float* __restrict__ W2l,
    const float* __restrict__ W2r, unsigned short* __restrict__ Wt,
    unsigned short* __restrict__ Wt2) {
  int n = blockIdx.x;
  int k = threadIdx.x;
  if (n < 512) {
    float v = (n < 256) ? W1l[k * 256 + n] : W1r[k * 256 + (n - 256)];
    Wt[n * 256 + k] = f2bf(v);
  } else {
    int c = n - 512;       // 0..31
    float v = (c < 16) ? W2l[k * 16 + c] : W2r[k * 16 + (c - 16)];
    Wt2[c * 256 + k] = f2bf(v);
  }
}

// ---------------- MFMA GEMM: M=2N rows (x1|x2), 128x128 tile, 8 waves, BK=64 ----------------
#define LDT 72
__global__ __launch_bounds__(512) void gemm_mfma_kernel(
    const float* __restrict__ X1, const float* __restrict__ X2,
    const unsigned short* __restrict__ Bt,
    unsigned short* __restrict__ xlb, unsigned short* __restrict__ xrb,
    int M, int NN) {
  __shared__ __align__(16) unsigned short As[128 * LDT];
  __shared__ __align__(16) unsigned short Bs[128 * LDT];
  int tid = threadIdx.x;
  int G = gridDim.x;
  int q = G >> 3, r = G & 7;
  int b = blockIdx.x;
  int xcd = b & 7, pos = b >> 3;
  int swz = (xcd < r) ? xcd * (q + 1) + pos : r * (q + 1) + (xcd - r) * q + pos;
  int row0 = (swz >> 2) * 128;
  int col0 = (swz & 3) * 128;
  int wid = tid >> 6, lane = tid & 63;
  int wr = wid >> 2, wc = wid & 3;
  int r16 = lane & 15, kb = (lane >> 4) * 8;

  f32x4v acc[4][2];
#pragma unroll
  for (int m = 0; m < 4; m++)
#pragma unroll
    for (int n = 0; n < 2; n++)
#pragma unroll
      for (int qq = 0; qq < 4; qq++) acc[m][n][qq] = 0.f;

  for (int k0 = 0; k0 < 256; k0 += 64) {
#pragma unroll
    for (int it = 0; it < 2; it++) {
      int g = tid + it * 512;
      int rr = g >> 3;
      int ko = (g & 7) * 8;
      int gr = row0 + rr;
      float4 a0 = make_float4(0.f, 0.f, 0.f, 0.f);
      float4 a1 = make_float4(0.f, 0.f, 0.f, 0.f);
      if (gr < M) {
        const float* src = (gr < NN) ? &X1[(size_t)gr * 256]
                                     : &X2[(size_t)(gr - NN) * 256];
        a0 = *(const float4*)&src[k0 + ko];
        a1 = *(const float4*)&src[k0 + ko + 4];
      }
      ushort4 lo, hi;
      lo.x = f2bf(a0.x); lo.y = f2bf(a0.y); lo.z = f2bf(a0.z); lo.w = f2bf(a0.w);
      hi.x = f2bf(a1.x); hi.y = f2bf(a1.y); hi.z = f2bf(a1.z); hi.w = f2bf(a1.w);
      *(ushort4*)&As[rr * LDT + ko] = lo;
      *(ushort4*)&As[rr * LDT + ko + 4] = hi;
      int4 bv = *(const int4*)&Bt[(size_t)(col0 + rr) * 256 + k0 + ko];
      *(int4*)&Bs[rr * LDT + ko] = bv;
    }
    __syncthreads();
#pragma unroll
    for (int kk = 0; kk < 64; kk += 32) {
      bf16x8 af[4], bfr[2];
#pragma unroll
      for (int m = 0; m < 4; m++)
        af[m] = *(const bf16x8*)&As[(wr * 64 + m * 16 + r16) * LDT + kk + kb];
#pragma unroll
      for (int n = 0; n < 2; n++)
        bfr[n] = *(const bf16x8*)&Bs[(wc * 32 + n * 16 + r16) * LDT + kk + kb];
#pragma unroll
      for (int m = 0; m < 4; m++)
#pragma unroll
        for (int n = 0; n < 2; n++)
          acc[m][n] = __builtin_amdgcn_mfma_f32_16x16x32_bf16(af[m], bfr[n], acc[m][n], 0, 0, 0);
    }
    __syncthreads();
  }
  unsigned short* Cb = (col0 < 256) ? xlb : xrb;
  int cbase = (col0 & 255) + wc * 32;
  int rq = (lane >> 4) * 4;
#pragma unroll
  for (int m = 0; m < 4; m++) {
#pragma unroll
    for (int n = 0; n < 2; n++) {
#pragma unroll
      for (int qq = 0; qq < 4; qq++) {
        int gr = row0 + wr * 64 + m * 16 + rq + qq;
        if (gr < M) {
          Cb[(size_t)gr * 256 + cbase + n * 16 + r16] = f2bf(acc[m][n][qq]);
        }
      }
    }
  }
}

// ---------------- layer-2 MFMA GEMM ----------------
#define LDB2 264
__global__ __launch_bounds__(256) void gemm2_mfma_kernel(
    const unsigned short* __restrict__ A, const unsigned short* __restrict__ Bt,
    unsigned short* __restrict__ xl2b, unsigned short* __restrict__ xr2b, int M) {
  __shared__ __align__(16) unsigned short As[256 * LDT];
  __shared__ __align__(16) unsigned short Bs[32 * LDB2];
  int tid = threadIdx.x;
  int row0 = blockIdx.x * 256;
  int wid = tid >> 6, lane = tid & 63;
  int r16 = lane & 15, kb = (lane >> 4) * 8, rq = (lane >> 4) * 4;

#pragma unroll
  for (int it = 0; it < 4; it++) {
    int g = tid + it * 256;
    int rr = g >> 5;
    int ko = (g & 31) * 8;
    *(int4*)&Bs[rr * LDB2 + ko] = *(const int4*)&Bt[rr * 256 + ko];
  }

  f32x4v acc[4][2];
#pragma unroll
  for (int m = 0; m < 4; m++)
#pragma unroll
    for (int n = 0; n < 2; n++)
#pragma unroll
      for (int qq = 0; qq < 4; qq++) acc[m][n][qq] = 0.f;

  for (int k0 = 0; k0 < 256; k0 += 64) {
#pragma unroll
    for (int it = 0; it < 8; it++) {
      int g = tid + it * 256;
      int rr = g >> 3;
      int ko = (g & 7) * 8;
      int gr = row0 + rr;
      int4 av = make_int4(0, 0, 0, 0);
      if (gr < M) av = *(const int4*)&A[(size_t)gr * 256 + k0 + ko];
      *(int4*)&As[rr * LDT + ko] = av;
    }
    __syncthreads();
#pragma unroll
    for (int kk = 0; kk < 64; kk += 32) {
      bf16x8 af[4], bfr[2];
#pragma unroll
      for (int m = 0; m < 4; m++)
        af[m] = *(const bf16x8*)&As[(wid * 64 + m * 16 + r16) * LDT + kk + kb];
#pragma unroll
      for (int n = 0; n < 2; n++)
        bfr[n] = *(const bf16x8*)&Bs[(n * 16 + r16) * LDB2 + k0 + kk + kb];
#pragma unroll
      for (int m = 0; m < 4; m++)
#pragma unroll
        for (int n = 0; n < 2; n++)
          acc[m][n] = __builtin_amdgcn_mfma_f32_16x16x32_bf16(af[m], bfr[n], acc[m][n], 0, 0, 0);
    }
    __syncthreads();
  }
#pragma unroll
  for (int m = 0; m < 4; m++) {
#pragma unroll
    for (int qq = 0; qq < 4; qq++) {
      int gr = row0 + wid * 64 + m * 16 + rq + qq;
      if (gr < M) {
        xl2b[(size_t)gr * 16 + r16] = f2bf(acc[m][0][qq]);
        xr2b[(size_t)gr * 16 + r16] = f2bf(acc[m][1][qq]);
      }
    }
  }
}

// ---------------- fused GATv2 layer 1: 4 edges/iter, 2 groups in flight, exp2-domain ----------------
__global__ __launch_bounds__(256) void gat1_kernel(const unsigned short* __restrict__ xlb,
    unsigned short* xrb, const float* __restrict__ att, const float* __restrict__ bias,
    const int* __restrict__ offs, const int* __restrict__ csr, int M) {
  int w = threadIdx.x >> 6, lane = threadIdx.x & 63;
  int i = blockIdx.x * 4 + w;
  if (i >= M) return;
  i = __builtin_amdgcn_readfirstlane(i);
  const uint2* rows = (const uint2*)xlb;
  uint2 ul = rows[(size_t)i * 64 + lane];
  uint2 ur = ((const uint2*)(xrb + (size_t)i * 256))[lane];
  f32x2 xl01 = bfpair(ul.x), xl23 = bfpair(ul.y);
  f32x2 xr01 = bfpair(ur.x), xr23 = bfpair(ur.y);
  float4 a4 = ((const float4*)att)[lane];
  f32x2 a01; a01.x = a4.x * LOG2E; a01.y = a4.y * LOG2E;   // exp2-domain scores
  f32x2 a23; a23.x = a4.z * LOG2E; a23.y = a4.w * LOG2E;

  // self-loop
  f32x2 t01 = xl01 + xr01, t23 = xl23 + xr23;
  f32x2 l01 = __builtin_elementwise_max(t01, t01 * NEG);
  f32x2 l23 = __builtin_elementwise_max(t23, t23 * NEG);
  f32x2 ps = l01 * a01 + l23 * a23;
  float p = ps.x + ps.y;
  p += __shfl_xor(p, 1, 8);
  p += __shfl_xor(p, 2, 8);
  p += __shfl_xor(p, 4, 8);
  float m = p, ssum = 1.f;
  f32x2 O01 = xl01, O23 = xl23;

  int e0 = offs[i], end = offs[i + 1];
  int rem = end - e0;
  int iters = (rem + 3) >> 2;

  uint2 ua0, ua1, ua2, ua3, ub0, ub1, ub2, ub3;
  {
    int idx0 = e0 + 0, idx1 = e0 + 1, idx2 = e0 + 2, idx3 = e0 + 3;
    int j0 = __builtin_amdgcn_readfirstlane(idx0 < end ? csr[idx0] : i);
    int j1 = __builtin_amdgcn_readfirstlane(idx1 < end ? csr[idx1] : i);
    int j2 = __builtin_amdgcn_readfirstlane(idx2 < end ? csr[idx2] : i);
    int j3 = __builtin_amdgcn_readfirstlane(idx3 < end ? csr[idx3] : i);
    ua0 = rows[(size_t)j0 * 64 + lane];
    ua1 = rows[(size_t)j1 * 64 + lane];
    ua2 = rows[(size_t)j2 * 64 + lane];
    ua3 = rows[(size_t)j3 * 64 + lane];
    idx0 += 4; idx1 += 4; idx2 += 4; idx3 += 4;
    j0 = __builtin_amdgcn_readfirstlane(idx0 < end ? csr[idx0] : i);
    j1 = __builtin_amdgcn_readfirstlane(idx1 < end ? csr[idx1] : i);
    j2 = __builtin_amdgcn_readfirstlane(idx2 < end ? csr[idx2] : i);
    j3 = __builtin_amdgcn_readfirstlane(idx3 < end ? csr[idx3] : i);
    ub0 = rows[(size_t)j0 * 64 + lane];
    ub1 = rows[(size_t)j1 * 64 + lane];
    ub2 = rows[(size_t)j2 * 64 + lane];
    ub3 = rows[(size_t)j3 * 64 + lane];
  }

  for (int t = 0; t < iters; t++) {
    int nb = e0 + (t + 2) * 4;
    int j0 = __builtin_amdgcn_readfirstlane(nb + 0 < end ? csr[nb + 0] : i);
    int j1 = __builtin_amdgcn_readfirstlane(nb + 1 < end ? csr[nb + 1] : i);
    int j2 = __builtin_amdgcn_readfirstlane(nb + 2 < end ? csr[nb + 2] : i);
    int j3 = __builtin_amdgcn_readfirstlane(nb + 3 < end ? csr[nb + 3] : i);
    uint2 un0 = rows[(size_t)j0 * 64 + lane];
    uint2 un1 = rows[(size_t)j1 * 64 + lane];
    uint2 un2 = rows[(size_t)j2 * 64 + lane];
    uint2 un3 = rows[(size_t)j3 * 64 + lane];

    // compute group A (4 edges)
    f32x2 x0a = bfpair(ua0.x), x0b = bfpair(ua0.y);
    f32x2 x1a = bfpair(ua1.x), x1b = bfpair(ua1.y);
    f32x2 x2a = bfpair(ua2.x), x2b = bfpair(ua2.y);
    f32x2 x3a = bfpair(ua3.x), x3b = bfpair(ua3.y);
    f32x2 q0a = x0a + xr01, q0b = x0b + xr23;
    f32x2 q1a = x1a + xr01, q1b = x1b + xr23;
    f32x2 q2a = x2a + xr01, q2b = x2b + xr23;
    f32x2 q3a = x3a + xr01, q3b = x3b + xr23;
    q0a = __builtin_elementwise_max(q0a, q0a * NEG);
    q0b = __builtin_elementwise_max(q0b, q0b * NEG);
    q1a = __builtin_elementwise_max(q1a, q1a * NEG);
    q1b = __builtin_elementwise_max(q1b, q1b * NEG);
    q2a = __builtin_elementwise_max(q2a, q2a * NEG);
    q2b = __builtin_elementwise_max(q2b, q2b * NEG);
    q3a = __builtin_elementwise_max(q3a, q3a * NEG);
    q3b = __builtin_elementwise_max(q3b, q3b * NEG);
    f32x2 s0 = q0a * a01 + q0b * a23;
    f32x2 s1 = q1a * a01 + q1b * a23;
    f32x2 s2 = q2a * a01 + q2b * a23;
    f32x2 s3 = q3a * a01 + q3b * a23;
    float p0 = s0.x + s0.y, p1 = s1.x + s1.y, p2 = s2.x + s2.y, p3 = s3.x + s3.y;
    p0 += __shfl_xor(p0, 1, 8);
    p1 += __shfl_xor(p1, 1, 8);
    p2 += __shfl_xor(p2, 1, 8);
    p3 += __shfl_xor(p3, 1, 8);
    p0 += __shfl_xor(p0, 2, 8);
    p1 += __shfl_xor(p1, 2, 8);
    p2 += __shfl_xor(p2, 2, 8);
    p3 += __shfl_xor(p3, 2, 8);
    p0 += __shfl_xor(p0, 4, 8);
    p1 += __shfl_xor(p1, 4, 8);
    p2 += __shfl_xor(p2, 4, 8);
    p3 += __shfl_xor(p3, 4, 8);
    int base = e0 + t * 4;
    if (base + 1 >= end) p1 = -3.0e38f;   // invalid slots -> w = 0
    if (base + 2 >= end) p2 = -3.0e38f;
    if (base + 3 >= end) p3 = -3.0e38f;
    float mx = fmaxf(fmaxf(p0, p1), fmaxf(p2, p3));
    if (!__all(mx <= m + 8.f)) {          // defer-max (T13), log2 units
      float mn = fmaxf(m, mx);
      float sc = exp2f(m - mn);
      O01 *= sc; O23 *= sc; ssum *= sc; m = mn;
    }
    float w0 = exp2f(p0 - m), w1 = exp2f(p1 - m);
    float w2 = exp2f(p2 - m), w3 = exp2f(p3 - m);
    O01 += w0 * x0a + w1 * x1a;
    O23 += w0 * x0b + w1 * x1b;
    O01 += w2 * x2a + w3 * x3a;
    O23 += w2 * x2b + w3 * x3b;
    ssum += (w0 + w1) + (w2 + w3);
    // rotate
    ua0 = ub0; ua1 = ub1; ua2 = ub2; ua3 = ub3;
    ub0 = un0; ub1 = un1; ub2 = un2; ub3 = un3;
  }

  float inv = 1.f / (ssum + 1e-16f);
  float4 b4 = ((const float4*)bias)[lane];
  float h0 = O01.x * inv + b4.x;
  float h1 = O01.y * inv + b4.y;
  float h2 = O23.x * inv + b4.z;
  float h3 = O23.y * inv + b4.w;
  h0 = h0 > 0.f ? h0 : (__expf(h0) - 1.f);
  h1 = h1 > 0.f ? h1 : (__expf(h1) - 1.f);
  h2 = h2 > 0.f ? h2 : (__expf(h2) - 1.f);
  h3 = h3 > 0.f ? h3 : (__expf(h3) - 1.f);
  ushort4 o;
  o.x = f2bf(h0); o.y = f2bf(h1); o.z = f2bf(h2); o.w = f2bf(h3);
  ((ushort4*)(xrb + (size_t)i * 256))[lane] = o;   // h aliases xr (own row only)
}

// ---------------- fused GATv2 layer 2: 4 edges/iter, exp2-domain ----------------
__global__ __launch_bounds__(256) void gat2_kernel(const unsigned short* __restrict__ xl2b,
    const unsigned short* __restrict__ xr2b, const float* __restrict__ att,
    const float* __restrict__ b2, const int* __restrict__ offs,
    const int* __restrict__ csr, float* __restrict__ y2, int M) {
  int grp = threadIdx.x >> 4, c = threadIdx.x & 15;
  int i = blockIdx.x * 16 + grp;
  if (i >= M) return;
  float xli = bf2f(xl2b[(size_t)i * 16 + c]);
  float xri = bf2f(xr2b[(size_t)i * 16 + c]);
  float a = att[c] * LOG2E;
  float v = xli + xri; v = fmaxf(v, NEG * v);
  float p = v * a;
#pragma unroll
  for (int o = 8; o >= 1; o >>= 1) p += __shfl_xor(p, o, 16);
  float m = p, ssum = 1.0f, O = xli;

  int e0 = offs[i], end = offs[i + 1];
  int rem = end - e0;
  int iters = (rem + 3) >> 2;

  float xa0, xa1, xa2, xa3, xb0, xb1, xb2, xb3;
  {
    int j0 = (e0 + 0 < end) ? csr[e0 + 0] : i;
    int j1 = (e0 + 1 < end) ? csr[e0 + 1] : i;
    int j2 = (e0 + 2 < end) ? csr[e0 + 2] : i;
    int j3 = (e0 + 3 < end) ? csr[e0 + 3] : i;
    xa0 = bf2f(xl2b[(size_t)j0 * 16 + c]);
    xa1 = bf2f(xl2b[(size_t)j1 * 16 + c]);
    xa2 = bf2f(xl2b[(size_t)j2 * 16 + c]);
    xa3 = bf2f(xl2b[(size_t)j3 * 16 + c]);
    j0 = (e0 + 4 < end) ? csr[e0 + 4] : i;
    j1 = (e0 + 5 < end) ? csr[e0 + 5] : i;
    j2 = (e0 + 6 < end) ? csr[e0 + 6] : i;
    j3 = (e0 + 7 < end) ? csr[e0 + 7] : i;
    xb0 = bf2f(xl2b[(size_t)j0 * 16 + c]);
    xb1 = bf2f(xl2b[(size_t)j1 * 16 + c]);
    xb2 = bf2f(xl2b[(size_t)j2 * 16 + c]);
    xb3 = bf2f(xl2b[(size_t)j3 * 16 + c]);
  }

  for (int t = 0; t < iters; t++) {
    int nb = e0 + (t + 2) * 4;
    int j0 = (nb + 0 < end) ? csr[nb + 0] : i;
    int j1 = (nb + 1 < end) ? csr[nb + 1] : i;
    int j2 = (nb + 2 < end) ? csr[nb + 2] : i;
    int j3 = (nb + 3 < end) ? csr[nb + 3] : i;
    float xn0 = bf2f(xl2b[(size_t)j0 * 16 + c]);
    float xn1 = bf2f(xl2b[(size_t)j1 * 16 + c]);
    float xn2 = bf2f(xl2b[(size_t)j2 * 16 + c]);
    float xn3 = bf2f(xl2b[(size_t)j3 * 16 + c]);

    float q0 = xa0 + xri; q0 = fmaxf(q0, NEG * q0);
    float q1 = xa1 + xri; q1 = fmaxf(q1, NEG * q1);
    float q2 = xa2 + xri; q2 = fmaxf(q2, NEG * q2);
    float q3 = xa3 + xri; q3 = fmaxf(q3, NEG * q3);
    float p0 = q0 * a, p1 = q1 * a, p2 = q2 * a, p3 = q3 * a;
#pragma unroll
    for (int o = 8; o >= 1; o >>= 1) {
      p0 += __shfl_xor(p0, o, 16);
      p1 += __shfl_xor(p1, o, 16);
      p2 += __shfl_xor(p2, o, 16);
      p3 += __shfl_xor(p3, o, 16);
    }
    int base = e0 + t * 4;
    if (base + 1 >= end) p1 = -3.0e38f;
    if (base + 2 >= end) p2 = -3.0e38f;
    if (base + 3 >= end) p3 = -3.0e38f;
    float mx = fmaxf(fmaxf(p0, p1), fmaxf(p2, p3));
    if (!__all(mx <= m + 8.f)) {
      float mn = fmaxf(m, mx);
      float sc = exp2f(m - mn);
      O *= sc; ssum *= sc; m = mn;
    }
    float w0 = exp2f(p0 - m), w1 = exp2f(p1 - m);
    float w2 = exp2f(p2 - m), w3 = exp2f(p3 - m);
    O += w0 * xa0 + w1 * xa1 + w2 * xa2 + w3 * xa3;
    ssum += (w0 + w1) + (w2 + w3);
    xa0 = xb0; xa1 = xb1; xa2 = xb2; xa3 = xb3;
    xb0 = xn0; xb1 = xn1; xb2 = xn2; xb3 = xn3;
  }
  y2[(size_t)i * C2 + c] = O / (ssum + 1e-16f) + b2[c];
}

// ---------------- finalize ----------------
__global__ __launch_bounds__(256) void finalize_kernel(const float* __restrict__ y,
    const float* __restrict__ z, float* __restrict__ out, int N) {
  int grp = threadIdx.x >> 4, c = threadIdx.x & 15;
  int i = blockIdx.x * 16 + grp;
  if (i >= N) return;
  float yv = y[(size_t)i * C2 + c];
  float zv = z[(size_t)i * C2 + c];
  float my = yv;
#pragma unroll
  for (int o = 8; o >= 1; o >>= 1) my = fmaxf(my, __shfl_xor(my, o, 16));
  float sy = __expf(yv - my);
#pragma unroll
  for (int o = 8; o >= 1; o >>= 1) sy += __shfl_xor(sy, o, 16);
  float lpy = yv - my - __logf(sy);
  float mz = zv;
#pragma unroll
  for (int o = 8; o >= 1; o >>= 1) mz = fmaxf(mz, __shfl_xor(mz, o, 16));
  float sz = __expf(zv - mz);
#pragma unroll
  for (int o = 8; o >= 1; o >>= 1) sz += __shfl_xor(sz, o, 16);
  float lpz = zv - mz - __logf(sz);
  float dot = yv * zv, ny2 = yv * yv, nz2 = zv * zv;
#pragma unroll
  for (int o = 8; o >= 1; o >>= 1) {
    dot += __shfl_xor(dot, o, 16);
    ny2 += __shfl_xor(ny2, o, 16);
    nz2 += __shfl_xor(nz2, o, 16);
  }
  float ny = fmaxf(sqrtf(ny2), 1e-8f);
  float nz = fmaxf(sqrtf(nz2), 1e-8f);
  float cosv = dot / (ny * nz);
  size_t o1 = (size_t)N * C2;
  size_t o2 = o1 + N;
  size_t o3 = o2 + (size_t)N * C2;
  size_t o4 = o3 + (size_t)N * C2;
  size_t idx = (size_t)i * C2 + c;
  out[idx] = lpy;
  if (c == 0) out[o1 + i] = 1.0f - cosv;
  out[o2 + idx] = lpz;
  out[o3 + idx] = lpy;
  out[o4 + idx] = lpy;
}

extern "C" void kernel_launch(void* const* d_in, const int* in_sizes, int n_in,
                              void* d_out, int out_size, void* d_ws, size_t ws_size,
                              hipStream_t stream) {
  const float* x1   = (const float*)d_in[0];
  const int*   ei1  = (const int*)d_in[1];
  const float* x2   = (const float*)d_in[2];
  const int*   ei2  = (const int*)d_in[3];
  const float* W1l  = (const float*)d_in[4];
  const float* W1r  = (const float*)d_in[5];
  const float* att1 = (const float*)d_in[6];
  const float* b1   = (const float*)d_in[7];
  const float* W2l  = (const float*)d_in[8];
  const float* W2r  = (const float*)d_in[9];
  const float* att2 = (const float*)d_in[10];
  const float* b2   = (const float*)d_in[11];
  const int N = in_sizes[0] / FIN;
  const int E = in_sizes[1] / 2;
  const int M = 2 * N;
  float* out = (float*)d_out;

  char* w = (char*)d_ws;
  size_t off = 0;
  auto carve = [&](size_t bytes) -> void* {
    void* p = w + off;
    off += (bytes + 255) & ~(size_t)255;
    return p;
  };
  unsigned short* xlb  = (unsigned short*)carve((size_t)M * 256 * 2);
  unsigned short* xrb  = (unsigned short*)carve((size_t)M * 256 * 2);
  unsigned short* Wt   = (unsigned short*)carve(512 * 256 * 2);
  unsigned short* Wt2  = (unsigned short*)carve(32 * 256 * 2);
  unsigned short* xl2b = (unsigned short*)carve((size_t)M * 16 * 2);
  unsigned short* xr2b = (unsigned short*)carve((size_t)M * 16 * 2);
  float* y2  = (float*)carve((size_t)M * 16 * 4);
  int* deg  = (int*)carve((size_t)M * 4);
  int* cnt  = (int*)carve((size_t)M * 4);
  int* offs = (int*)carve((size_t)(M + 1) * 4);
  int* csr  = (int*)carve((size_t)2 * E * 4);
  int* partials = (int*)carve(128 * 4);
  (void)ws_size; (void)n_in; (void)out_size;

  const size_t zero_bytes = (size_t)((char*)cnt - (char*)deg) + (size_t)M * 4;
  hipMemsetAsync(deg, 0, zero_bytes, stream);

  const int NB = (M + 1023) / 1024;
  const int EQ = (E + 3) >> 2;

  cvt_w_kernel<<<544, 256, 0, stream>>>(W1l, W1r, W2l, W2r, Wt, Wt2);

  deg_kernel<<<(2 * EQ + 255) / 256, 256, 0, stream>>>(ei1, ei2, deg, E, N);
  scan_part_kernel<<<NB, 1024, 0, stream>>>(deg, offs, partials, M);
  scan_fix_kernel<<<NB, 1024, 0, stream>>>(offs, partials, NB, M);
  fill_kernel<<<(2 * EQ + 255) / 256, 256, 0, stream>>>(ei1, ei2, offs, cnt, csr, E, N);

  int RB = (M + 127) / 128;
  gemm_mfma_kernel<<<RB * 4, 512, 0, stream>>>(x1, x2, Wt, xlb, xrb, M, N);
  gat1_kernel<<<(M + 3) / 4, 256, 0, stream>>>(xlb, xrb, att1, b1, offs, csr, M);
  gemm2_mfma_kernel<<<(M + 255) / 256, 256, 0, stream>>>(xrb, Wt2, xl2b, xr2b, M);
  gat2_kernel<<<(M + 15) / 16, 256, 0, stream>>>(xl2b, xr2b, att2, b2, offs, csr, y2, M);

  finalize_kernel<<<(N + 15) / 16, 256, 0, stream>>>(y2, y2 + (size_t)N * 16, out, N);
}

// Round 12
// 410.903 us; speedup vs baseline: 1.0272x; 1.0272x over previous
//
#include <hip/hip_runtime.h>
#include <hip/hip_bf16.h>
#include <math.h>

#define FIN 256
#define C2  16
#define NEG 0.2f
#define LOG2E 1.4426950408889634f

typedef short bf16x8 __attribute__((ext_vector_type(8)));
typedef float f32x4v __attribute__((ext_vector_type(4)));
typedef float f32x2 __attribute__((ext_vector_type(2)));

__device__ __forceinline__ float bf2f(unsigned short u) {
  union { float f; unsigned int i; } c; c.i = ((unsigned int)u) << 16; return c.f;
}
__device__ __forceinline__ unsigned short f2bf(float f) {
  __hip_bfloat16 b = __float2bfloat16(f);
  return *(unsigned short*)&b;
}
__device__ __forceinline__ f32x2 bfpair(unsigned int u) {
  union { float f; unsigned int i; } lo, hi;
  lo.i = u << 16;
  hi.i = u & 0xffff0000u;
  f32x2 r; r.x = lo.f; r.y = hi.f; return r;
}

// ---------------- CSR build (both graphs, int4-vectorized) ----------------
__global__ __launch_bounds__(256) void deg_kernel(const int* __restrict__ ei1,
    const int* __restrict__ ei2, int* __restrict__ deg, int E, int N) {
  int EQ = (E + 3) >> 2;
  int q = blockIdx.x * 256 + threadIdx.x;
  if (q >= 2 * EQ) return;
  int g = q >= EQ;
  int lq = g ? q - EQ : q;
  const int* dstp = (g ? ei2 : ei1) + E;
  int base = g * N;
  int e0 = lq * 4;
  if (e0 + 3 < E) {
    int4 d4 = *(const int4*)&dstp[e0];
    atomicAdd(&deg[base + d4.x], 1);
    atomicAdd(&deg[base + d4.y], 1);
    atomicAdd(&deg[base + d4.z], 1);
    atomicAdd(&deg[base + d4.w], 1);
  } else {
    for (int k = 0; k < 4 && e0 + k < E; k++)
      atomicAdd(&deg[base + dstp[e0 + k]], 1);
  }
}

__global__ __launch_bounds__(1024) void scan_part_kernel(const int* __restrict__ deg,
    int* __restrict__ offs, int* __restrict__ partials, int n) {
  __shared__ int wsum[16], wpref[16];
  int tid = threadIdx.x, lane = tid & 63, wid = tid >> 6;
  int idx = blockIdx.x * 1024 + tid;
  int v = (idx < n) ? deg[idx] : 0;
  int s = v;
#pragma unroll
  for (int o = 1; o < 64; o <<= 1) {
    int t = __shfl_up(s, o, 64);
    if (lane >= o) s += t;
  }
  if (lane == 63) wsum[wid] = s;
  __syncthreads();
  if (tid < 16) {
    int t = wsum[tid];
    int ss = t;
#pragma unroll
    for (int o = 1; o < 16; o <<= 1) {
      int u = __shfl_up(ss, o, 16);
      if (tid >= o) ss += u;
    }
    wpref[tid] = ss - t;
    if (tid == 15) partials[blockIdx.x] = ss;
  }
  __syncthreads();
  if (idx < n) offs[idx] = wpref[wid] + s - v;
}

__global__ __launch_bounds__(1024) void scan_fix_kernel(int* __restrict__ offs,
    const int* __restrict__ partials, int nb, int n) {
  __shared__ int wsum[16], wpref[16];
  __shared__ int carry_s;
  int tid = threadIdx.x, lane = tid & 63, wid = tid >> 6;
  int v = (tid < nb) ? partials[tid] : 0;
  int s = v;
#pragma unroll
  for (int o = 1; o < 64; o <<= 1) {
    int t = __shfl_up(s, o, 64);
    if (lane >= o) s += t;
  }
  if (lane == 63) wsum[wid] = s;
  __syncthreads();
  if (tid < 16) {
    int t = wsum[tid];
    int ss = t;
#pragma unroll
    for (int o = 1; o < 16; o <<= 1) {
      int u = __shfl_up(ss, o, 16);
      if (tid >= o) ss += u;
    }
    wpref[tid] = ss - t;
  }
  __syncthreads();
  s += wpref[wid];
  int b = blockIdx.x;
  if (b == 0) {
    if (tid == nb - 1) offs[n] = s;
  } else if (tid == b - 1) {
    carry_s = s;
  }
  __syncthreads();
  if (b > 0) {
    int idx = b * 1024 + tid;
    if (idx < n) offs[idx] += carry_s;
  }
}

__global__ __launch_bounds__(256) void fill_kernel(const int* __restrict__ ei1,
    const int* __restrict__ ei2, const int* __restrict__ offs,
    int* __restrict__ cnt, int* __restrict__ csr, int E, int N) {
  int EQ = (E + 3) >> 2;
  int q = blockIdx.x * 256 + threadIdx.x;
  if (q >= 2 * EQ) return;
  int g = q >= EQ;
  int lq = g ? q - EQ : q;
  const int* ei = g ? ei2 : ei1;
  int base = g * N;
  int e0 = lq * 4;
  if (e0 + 3 < E) {
    int4 s4 = *(const int4*)&ei[e0];
    int4 d4 = *(const int4*)&ei[E + e0];
    int n0 = base + d4.x, n1 = base + d4.y, n2 = base + d4.z, n3 = base + d4.w;
    csr[offs[n0] + atomicAdd(&cnt[n0], 1)] = base + s4.x;
    csr[offs[n1] + atomicAdd(&cnt[n1], 1)] = base + s4.y;
    csr[offs[n2] + atomicAdd(&cnt[n2], 1)] = base + s4.z;
    csr[offs[n3] + atomicAdd(&cnt[n3], 1)] = base + s4.w;
  } else {
    for (int k = 0; k < 4 && e0 + k < E; k++) {
      int node = base + ei[E + e0 + k];
      csr[offs[node] + atomicAdd(&cnt[node], 1)] = base + ei[e0 + k];
    }
  }
}

// ---------------- weight converts (one launch) ----------------
__global__ __launch_bounds__(256) void cvt_w_kernel(const float* __restrict__ W1l,
    const float* __restrict__ W1r, const float* __restrict__ W2l,
    const float* __restrict__ W2r, unsigned short* __restrict__ Wt,
    unsigned short* __restrict__ Wt2) {
  int n = blockIdx.x;
  int k = threadIdx.x;
  if (n < 512) {
    float v = (n < 256) ? W1l[k * 256 + n] : W1r[k * 256 + (n - 256)];
    Wt[n * 256 + k] = f2bf(v);
  } else {
    int c = n - 512;
    float v = (c < 16) ? W2l[k * 16 + c] : W2r[k * 16 + (c - 16)];
    Wt2[c * 256 + k] = f2bf(v);
  }
}

// ---------------- MFMA GEMM: M=2N rows (x1|x2), 128x128 tile, 8 waves, BK=64 ----------------
#define LDT 72
__global__ __launch_bounds__(512) void gemm_mfma_kernel(
    const float* __restrict__ X1, const float* __restrict__ X2,
    const unsigned short* __restrict__ Bt,
    unsigned short* __restrict__ xlb, unsigned short* __restrict__ xrb,
    int M, int NN) {
  __shared__ __align__(16) unsigned short As[128 * LDT];
  __shared__ __align__(16) unsigned short Bs[128 * LDT];
  int tid = threadIdx.x;
  int G = gridDim.x;
  int q = G >> 3, r = G & 7;
  int b = blockIdx.x;
  int xcd = b & 7, pos = b >> 3;
  int swz = (xcd < r) ? xcd * (q + 1) + pos : r * (q + 1) + (xcd - r) * q + pos;
  int row0 = (swz >> 2) * 128;
  int col0 = (swz & 3) * 128;
  int wid = tid >> 6, lane = tid & 63;
  int wr = wid >> 2, wc = wid & 3;
  int r16 = lane & 15, kb = (lane >> 4) * 8;

  f32x4v acc[4][2];
#pragma unroll
  for (int m = 0; m < 4; m++)
#pragma unroll
    for (int n = 0; n < 2; n++)
#pragma unroll
      for (int qq = 0; qq < 4; qq++) acc[m][n][qq] = 0.f;

  for (int k0 = 0; k0 < 256; k0 += 64) {
#pragma unroll
    for (int it = 0; it < 2; it++) {
      int g = tid + it * 512;
      int rr = g >> 3;
      int ko = (g & 7) * 8;
      int gr = row0 + rr;
      float4 a0 = make_float4(0.f, 0.f, 0.f, 0.f);
      float4 a1 = make_float4(0.f, 0.f, 0.f, 0.f);
      if (gr < M) {
        const float* src = (gr < NN) ? &X1[(size_t)gr * 256]
                                     : &X2[(size_t)(gr - NN) * 256];
        a0 = *(const float4*)&src[k0 + ko];
        a1 = *(const float4*)&src[k0 + ko + 4];
      }
      ushort4 lo, hi;
      lo.x = f2bf(a0.x); lo.y = f2bf(a0.y); lo.z = f2bf(a0.z); lo.w = f2bf(a0.w);
      hi.x = f2bf(a1.x); hi.y = f2bf(a1.y); hi.z = f2bf(a1.z); hi.w = f2bf(a1.w);
      *(ushort4*)&As[rr * LDT + ko] = lo;
      *(ushort4*)&As[rr * LDT + ko + 4] = hi;
      int4 bv = *(const int4*)&Bt[(size_t)(col0 + rr) * 256 + k0 + ko];
      *(int4*)&Bs[rr * LDT + ko] = bv;
    }
    __syncthreads();
#pragma unroll
    for (int kk = 0; kk < 64; kk += 32) {
      bf16x8 af[4], bfr[2];
#pragma unroll
      for (int m = 0; m < 4; m++)
        af[m] = *(const bf16x8*)&As[(wr * 64 + m * 16 + r16) * LDT + kk + kb];
#pragma unroll
      for (int n = 0; n < 2; n++)
        bfr[n] = *(const bf16x8*)&Bs[(wc * 32 + n * 16 + r16) * LDT + kk + kb];
#pragma unroll
      for (int m = 0; m < 4; m++)
#pragma unroll
        for (int n = 0; n < 2; n++)
          acc[m][n] = __builtin_amdgcn_mfma_f32_16x16x32_bf16(af[m], bfr[n], acc[m][n], 0, 0, 0);
    }
    __syncthreads();
  }
  unsigned short* Cb = (col0 < 256) ? xlb : xrb;
  int cbase = (col0 & 255) + wc * 32;
  int rq = (lane >> 4) * 4;
#pragma unroll
  for (int m = 0; m < 4; m++) {
#pragma unroll
    for (int n = 0; n < 2; n++) {
#pragma unroll
      for (int qq = 0; qq < 4; qq++) {
        int gr = row0 + wr * 64 + m * 16 + rq + qq;
        if (gr < M) {
          Cb[(size_t)gr * 256 + cbase + n * 16 + r16] = f2bf(acc[m][n][qq]);
        }
      }
    }
  }
}

// ---------------- layer-2 MFMA GEMM ----------------
#define LDB2 264
__global__ __launch_bounds__(256) void gemm2_mfma_kernel(
    const unsigned short* __restrict__ A, const unsigned short* __restrict__ Bt,
    unsigned short* __restrict__ xl2b, unsigned short* __restrict__ xr2b, int M) {
  __shared__ __align__(16) unsigned short As[256 * LDT];
  __shared__ __align__(16) unsigned short Bs[32 * LDB2];
  int tid = threadIdx.x;
  int row0 = blockIdx.x * 256;
  int wid = tid >> 6, lane = tid & 63;
  int r16 = lane & 15, kb = (lane >> 4) * 8, rq = (lane >> 4) * 4;

#pragma unroll
  for (int it = 0; it < 4; it++) {
    int g = tid + it * 256;
    int rr = g >> 5;
    int ko = (g & 31) * 8;
    *(int4*)&Bs[rr * LDB2 + ko] = *(const int4*)&Bt[rr * 256 + ko];
  }

  f32x4v acc[4][2];
#pragma unroll
  for (int m = 0; m < 4; m++)
#pragma unroll
    for (int n = 0; n < 2; n++)
#pragma unroll
      for (int qq = 0; qq < 4; qq++) acc[m][n][qq] = 0.f;

  for (int k0 = 0; k0 < 256; k0 += 64) {
#pragma unroll
    for (int it = 0; it < 8; it++) {
      int g = tid + it * 256;
      int rr = g >> 3;
      int ko = (g & 7) * 8;
      int gr = row0 + rr;
      int4 av = make_int4(0, 0, 0, 0);
      if (gr < M) av = *(const int4*)&A[(size_t)gr * 256 + k0 + ko];
      *(int4*)&As[rr * LDT + ko] = av;
    }
    __syncthreads();
#pragma unroll
    for (int kk = 0; kk < 64; kk += 32) {
      bf16x8 af[4], bfr[2];
#pragma unroll
      for (int m = 0; m < 4; m++)
        af[m] = *(const bf16x8*)&As[(wid * 64 + m * 16 + r16) * LDT + kk + kb];
#pragma unroll
      for (int n = 0; n < 2; n++)
        bfr[n] = *(const bf16x8*)&Bs[(n * 16 + r16) * LDB2 + k0 + kk + kb];
#pragma unroll
      for (int m = 0; m < 4; m++)
#pragma unroll
        for (int n = 0; n < 2; n++)
          acc[m][n] = __builtin_amdgcn_mfma_f32_16x16x32_bf16(af[m], bfr[n], acc[m][n], 0, 0, 0);
    }
    __syncthreads();
  }
#pragma unroll
  for (int m = 0; m < 4; m++) {
#pragma unroll
    for (int qq = 0; qq < 4; qq++) {
      int gr = row0 + wid * 64 + m * 16 + rq + qq;
      if (gr < M) {
        xl2b[(size_t)gr * 16 + r16] = f2bf(acc[m][0][qq]);
        xr2b[(size_t)gr * 16 + r16] = f2bf(acc[m][1][qq]);
      }
    }
  }
}

// ---------------- fused GATv2 layer 1 (R10 structure: 1 wave/node, depth-3 pair pipeline, exp2) ----------------
__global__ __launch_bounds__(256) void gat1_kernel(const unsigned short* __restrict__ xlb,
    unsigned short* xrb, const float* __restrict__ att, const float* __restrict__ bias,
    const int* __restrict__ offs, const int* __restrict__ csr, int M) {
  int w = threadIdx.x >> 6, lane = threadIdx.x & 63;
  int i = blockIdx.x * 4 + w;
  if (i >= M) return;
  i = __builtin_amdgcn_readfirstlane(i);
  const uint2* rows = (const uint2*)xlb;
  uint2 ul = rows[(size_t)i * 64 + lane];
  uint2 ur = ((const uint2*)(xrb + (size_t)i * 256))[lane];
  f32x2 xl01 = bfpair(ul.x), xl23 = bfpair(ul.y);
  f32x2 xr01 = bfpair(ur.x), xr23 = bfpair(ur.y);
  float4 a4 = ((const float4*)att)[lane];
  f32x2 a01; a01.x = a4.x * LOG2E; a01.y = a4.y * LOG2E;   // exp2-domain
  f32x2 a23; a23.x = a4.z * LOG2E; a23.y = a4.w * LOG2E;

  f32x2 t01 = xl01 + xr01, t23 = xl23 + xr23;
  f32x2 l01 = __builtin_elementwise_max(t01, t01 * NEG);
  f32x2 l23 = __builtin_elementwise_max(t23, t23 * NEG);
  f32x2 ps = l01 * a01 + l23 * a23;
  float p = ps.x + ps.y;
  p += __shfl_xor(p, 1, 8);
  p += __shfl_xor(p, 2, 8);
  p += __shfl_xor(p, 4, 8);
  float m = p, ssum = 1.f;
  f32x2 O01 = xl01, O23 = xl23;

  int e = offs[i], end = offs[i + 1];
  int rem = end - e;

  int ja0 = __builtin_amdgcn_readfirstlane(rem > 0 ? csr[e + 0] : i);
  int ja1 = __builtin_amdgcn_readfirstlane(rem > 1 ? csr[e + 1] : i);
  uint2 ua0 = rows[(size_t)ja0 * 64 + lane];
  uint2 ua1 = rows[(size_t)ja1 * 64 + lane];
  int jb0 = __builtin_amdgcn_readfirstlane(rem > 2 ? csr[e + 2] : i);
  int jb1 = __builtin_amdgcn_readfirstlane(rem > 3 ? csr[e + 3] : i);
  uint2 ub0 = rows[(size_t)jb0 * 64 + lane];
  uint2 ub1 = rows[(size_t)jb1 * 64 + lane];
  int jc0 = __builtin_amdgcn_readfirstlane(rem > 4 ? csr[e + 4] : i);
  int jc1 = __builtin_amdgcn_readfirstlane(rem > 5 ? csr[e + 5] : i);
  uint2 uc0 = rows[(size_t)jc0 * 64 + lane];
  uint2 uc1 = rows[(size_t)jc1 * 64 + lane];

  while (rem >= 2) {
    int jn0 = __builtin_amdgcn_readfirstlane(rem > 6 ? csr[e + 6] : i);
    int jn1 = __builtin_amdgcn_readfirstlane(rem > 7 ? csr[e + 7] : i);
    uint2 un0 = rows[(size_t)jn0 * 64 + lane];
    uint2 un1 = rows[(size_t)jn1 * 64 + lane];
    f32x2 x001 = bfpair(ua0.x), x023 = bfpair(ua0.y);
    f32x2 x101 = bfpair(ua1.x), x123 = bfpair(ua1.y);
    f32x2 q01 = x001 + xr01, q23 = x023 + xr23;
    f32x2 r01 = x101 + xr01, r23 = x123 + xr23;
    f32x2 g01 = __builtin_elementwise_max(q01, q01 * NEG);
    f32x2 g23 = __builtin_elementwise_max(q23, q23 * NEG);
    f32x2 k01 = __builtin_elementwise_max(r01, r01 * NEG);
    f32x2 k23 = __builtin_elementwise_max(r23, r23 * NEG);
    f32x2 s0v = g01 * a01 + g23 * a23;
    f32x2 s1v = k01 * a01 + k23 * a23;
    float p0 = s0v.x + s0v.y;
    float p1 = s1v.x + s1v.y;
    p0 += __shfl_xor(p0, 1, 8);
    p1 += __shfl_xor(p1, 1, 8);
    p0 += __shfl_xor(p0, 2, 8);
    p1 += __shfl_xor(p1, 2, 8);
    p0 += __shfl_xor(p0, 4, 8);
    p1 += __shfl_xor(p1, 4, 8);
    float mx = fmaxf(p0, p1);
    if (!__all(mx <= m + 8.f)) {        // defer-max (T13), log2 units
      float mn = fmaxf(m, mx);
      float sc = exp2f(m - mn);
      O01 *= sc; O23 *= sc; ssum *= sc; m = mn;
    }
    float w0 = exp2f(p0 - m), w1 = exp2f(p1 - m);
    O01 += w0 * x001 + w1 * x101;
    O23 += w0 * x023 + w1 * x123;
    ssum += w0 + w1;
    ua0 = ub0; ua1 = ub1;
    ub0 = uc0; ub1 = uc1;
    uc0 = un0; uc1 = un1;
    e += 2; rem -= 2;
  }
  if (rem == 1) {
    f32x2 x001 = bfpair(ua0.x), x023 = bfpair(ua0.y);
    f32x2 q01 = x001 + xr01, q23 = x023 + xr23;
    f32x2 g01 = __builtin_elementwise_max(q01, q01 * NEG);
    f32x2 g23 = __builtin_elementwise_max(q23, q23 * NEG);
    f32x2 s0v = g01 * a01 + g23 * a23;
    float p0 = s0v.x + s0v.y;
    p0 += __shfl_xor(p0, 1, 8);
    p0 += __shfl_xor(p0, 2, 8);
    p0 += __shfl_xor(p0, 4, 8);
    if (!__all(p0 <= m + 8.f)) {
      float mn = fmaxf(m, p0);
      float sc = exp2f(m - mn);
      O01 *= sc; O23 *= sc; ssum *= sc; m = mn;
    }
    float w0 = exp2f(p0 - m);
    O01 += w0 * x001;
    O23 += w0 * x023;
    ssum += w0;
  }
  float inv = 1.f / (ssum + 1e-16f);
  float4 b4 = ((const float4*)bias)[lane];
  float h0 = O01.x * inv + b4.x;
  float h1 = O01.y * inv + b4.y;
  float h2 = O23.x * inv + b4.z;
  float h3 = O23.y * inv + b4.w;
  h0 = h0 > 0.f ? h0 : (__expf(h0) - 1.f);
  h1 = h1 > 0.f ? h1 : (__expf(h1) - 1.f);
  h2 = h2 > 0.f ? h2 : (__expf(h2) - 1.f);
  h3 = h3 > 0.f ? h3 : (__expf(h3) - 1.f);
  ushort4 o;
  o.x = f2bf(h0); o.y = f2bf(h1); o.z = f2bf(h2); o.w = f2bf(h3);
  ((ushort4*)(xrb + (size_t)i * 256))[lane] = o;   // h aliases xr (own row only)
}

// ---------------- fused GATv2 layer 2 (R10 structure: depth-3 pair pipeline, exp2) ----------------
__global__ __launch_bounds__(256) void gat2_kernel(const unsigned short* __restrict__ xl2b,
    const unsigned short* __restrict__ xr2b, const float* __restrict__ att,
    const float* __restrict__ b2, const int* __restrict__ offs,
    const int* __restrict__ csr, float* __restrict__ y2, int M) {
  int grp = threadIdx.x >> 4, c = threadIdx.x & 15;
  int i = blockIdx.x * 16 + grp;
  if (i >= M) return;
  float xli = bf2f(xl2b[(size_t)i * 16 + c]);
  float xri = bf2f(xr2b[(size_t)i * 16 + c]);
  float a = att[c] * LOG2E;
  float v = xli + xri; v = fmaxf(v, NEG * v);
  float p = v * a;
#pragma unroll
  for (int o = 8; o >= 1; o >>= 1) p += __shfl_xor(p, o, 16);
  float m = p, ssum = 1.0f, O = xli;

  int e = offs[i], end = offs[i + 1];
  int rem = end - e;

  int ja0 = rem > 0 ? csr[e + 0] : i;
  int ja1 = rem > 1 ? csr[e + 1] : i;
  float xa0 = bf2f(xl2b[(size_t)ja0 * 16 + c]);
  float xa1 = bf2f(xl2b[(size_t)ja1 * 16 + c]);
  int jb0 = rem > 2 ? csr[e + 2] : i;
  int jb1 = rem > 3 ? csr[e + 3] : i;
  float xb0 = bf2f(xl2b[(size_t)jb0 * 16 + c]);
  float xb1 = bf2f(xl2b[(size_t)jb1 * 16 + c]);
  int jc0 = rem > 4 ? csr[e + 4] : i;
  int jc1 = rem > 5 ? csr[e + 5] : i;
  float xc0 = bf2f(xl2b[(size_t)jc0 * 16 + c]);
  float xc1 = bf2f(xl2b[(size_t)jc1 * 16 + c]);

  while (rem >= 2) {
    int jn0 = rem > 6 ? csr[e + 6] : i;
    int jn1 = rem > 7 ? csr[e + 7] : i;
    float xn0 = bf2f(xl2b[(size_t)jn0 * 16 + c]);
    float xn1 = bf2f(xl2b[(size_t)jn1 * 16 + c]);
    float q0 = xa0 + xri; q0 = fmaxf(q0, NEG * q0);
    float q1 = xa1 + xri; q1 = fmaxf(q1, NEG * q1);
    float p0 = q0 * a, p1 = q1 * a;
#pragma unroll
    for (int o = 8; o >= 1; o >>= 1) {
      p0 += __shfl_xor(p0, o, 16);
      p1 += __shfl_xor(p1, o, 16);
    }
    float mx = fmaxf(p0, p1);
    if (!__all(mx <= m + 8.f)) {
      float mn = fmaxf(m, mx);
      float sc = exp2f(m - mn);
      O *= sc; ssum *= sc; m = mn;
    }
    float w0 = exp2f(p0 - m), w1 = exp2f(p1 - m);
    O += w0 * xa0 + w1 * xa1;
    ssum += w0 + w1;
    xa0 = xb0; xa1 = xb1;
    xb0 = xc0; xb1 = xc1;
    xc0 = xn0; xc1 = xn1;
    e += 2; rem -= 2;
  }
  if (rem == 1) {
    float q0 = xa0 + xri; q0 = fmaxf(q0, NEG * q0);
    float p0 = q0 * a;
#pragma unroll
    for (int o = 8; o >= 1; o >>= 1) p0 += __shfl_xor(p0, o, 16);
    if (!__all(p0 <= m + 8.f)) {
      float mn = fmaxf(m, p0);
      float sc = exp2f(m - mn);
      O *= sc; ssum *= sc; m = mn;
    }
    float w0 = exp2f(p0 - m);
    O += w0 * xa0;
    ssum += w0;
  }
  y2[(size_t)i * C2 + c] = O / (ssum + 1e-16f) + b2[c];
}

// ---------------- finalize ----------------
__global__ __launch_bounds__(256) void finalize_kernel(const float* __restrict__ y,
    const float* __restrict__ z, float* __restrict__ out, int N) {
  int grp = threadIdx.x >> 4, c = threadIdx.x & 15;
  int i = blockIdx.x * 16 + grp;
  if (i >= N) return;
  float yv = y[(size_t)i * C2 + c];
  float zv = z[(size_t)i * C2 + c];
  float my = yv;
#pragma unroll
  for (int o = 8; o >= 1; o >>= 1) my = fmaxf(my, __shfl_xor(my, o, 16));
  float sy = __expf(yv - my);
#pragma unroll
  for (int o = 8; o >= 1; o >>= 1) sy += __shfl_xor(sy, o, 16);
  float lpy = yv - my - __logf(sy);
  float mz = zv;
#pragma unroll
  for (int o = 8; o >= 1; o >>= 1) mz = fmaxf(mz, __shfl_xor(mz, o, 16));
  float sz = __expf(zv - mz);
#pragma unroll
  for (int o = 8; o >= 1; o >>= 1) sz += __shfl_xor(sz, o, 16);
  float lpz = zv - mz - __logf(sz);
  float dot = yv * zv, ny2 = yv * yv, nz2 = zv * zv;
#pragma unroll
  for (int o = 8; o >= 1; o >>= 1) {
    dot += __shfl_xor(dot, o, 16);
    ny2 += __shfl_xor(ny2, o, 16);
    nz2 += __shfl_xor(nz2, o, 16);
  }
  float ny = fmaxf(sqrtf(ny2), 1e-8f);
  float nz = fmaxf(sqrtf(nz2), 1e-8f);
  float cosv = dot / (ny * nz);
  size_t o1 = (size_t)N * C2;
  size_t o2 = o1 + N;
  size_t o3 = o2 + (size_t)N * C2;
  size_t o4 = o3 + (size_t)N * C2;
  size_t idx = (size_t)i * C2 + c;
  out[idx] = lpy;
  if (c == 0) out[o1 + i] = 1.0f - cosv;
  out[o2 + idx] = lpz;
  out[o3 + idx] = lpy;
  out[o4 + idx] = lpy;
}

extern "C" void kernel_launch(void* const* d_in, const int* in_sizes, int n_in,
                              void* d_out, int out_size, void* d_ws, size_t ws_size,
                              hipStream_t stream) {
  const float* x1   = (const float*)d_in[0];
  const int*   ei1  = (const int*)d_in[1];
  const float* x2   = (const float*)d_in[2];
  const int*   ei2  = (const int*)d_in[3];
  const float* W1l  = (const float*)d_in[4];
  const float* W1r  = (const float*)d_in[5];
  const float* att1 = (const float*)d_in[6];
  const float* b1   = (const float*)d_in[7];
  const float* W2l  = (const float*)d_in[8];
  const float* W2r  = (const float*)d_in[9];
  const float* att2 = (const float*)d_in[10];
  const float* b2   = (const float*)d_in[11];
  const int N = in_sizes[0] / FIN;
  const int E = in_sizes[1] / 2;
  const int M = 2 * N;
  float* out = (float*)d_out;

  char* w = (char*)d_ws;
  size_t off = 0;
  auto carve = [&](size_t bytes) -> void* {
    void* p = w + off;
    off += (bytes + 255) & ~(size_t)255;
    return p;
  };
  unsigned short* xlb  = (unsigned short*)carve((size_t)M * 256 * 2);
  unsigned short* xrb  = (unsigned short*)carve((size_t)M * 256 * 2);
  unsigned short* Wt   = (unsigned short*)carve(512 * 256 * 2);
  unsigned short* Wt2  = (unsigned short*)carve(32 * 256 * 2);
  unsigned short* xl2b = (unsigned short*)carve((size_t)M * 16 * 2);
  unsigned short* xr2b = (unsigned short*)carve((size_t)M * 16 * 2);
  float* y2  = (float*)carve((size_t)M * 16 * 4);
  int* deg  = (int*)carve((size_t)M * 4);
  int* cnt  = (int*)carve((size_t)M * 4);
  int* offs = (int*)carve((size_t)(M + 1) * 4);
  int* csr  = (int*)carve((size_t)2 * E * 4);
  int* partials = (int*)carve(128 * 4);
  (void)ws_size; (void)n_in; (void)out_size;

  const size_t zero_bytes = (size_t)((char*)cnt - (char*)deg) + (size_t)M * 4;
  hipMemsetAsync(deg, 0, zero_bytes, stream);

  const int NB = (M + 1023) / 1024;
  const int EQ = (E + 3) >> 2;

  cvt_w_kernel<<<544, 256, 0, stream>>>(W1l, W1r, W2l, W2r, Wt, Wt2);

  deg_kernel<<<(2 * EQ + 255) / 256, 256, 0, stream>>>(ei1, ei2, deg, E, N);
  scan_part_kernel<<<NB, 1024, 0, stream>>>(deg, offs, partials, M);
  scan_fix_kernel<<<NB, 1024, 0, stream>>>(offs, partials, NB, M);
  fill_kernel<<<(2 * EQ + 255) / 256, 256, 0, stream>>>(ei1, ei2, offs, cnt, csr, E, N);

  int RB = (M + 127) / 128;
  gemm_mfma_kernel<<<RB * 4, 512, 0, stream>>>(x1, x2, Wt, xlb, xrb, M, N);
  gat1_kernel<<<(M + 3) / 4, 256, 0, stream>>>(xlb, xrb, att1, b1, offs, csr, M);
  gemm2_mfma_kernel<<<(M + 255) / 256, 256, 0, stream>>>(xrb, Wt2, xl2b, xr2b, M);
  gat2_kernel<<<(M + 15) / 16, 256, 0, stream>>>(xl2b, xr2b, att2, b2, offs, csr, y2, M);

  finalize_kernel<<<(N + 15) / 16, 256, 0, stream>>>(y2, y2 + (size_t)N * 16, out, N);
}